// Round 10
// baseline (3685.693 us; speedup 1.0000x reference)
//
#include <hip/hip_runtime.h>
#include <stdint.h>

#define TT 512
#define BB 64
#define II 256
#define HS 512          // H
#define HHALF 256       // HH
#define R4H 2048        // 4*H
#define HB_STRIDE 16384 // (HS/2)*BB u32 entries per h buffer

// ---------------------------------------------------------------------------
// Phase 1: PG[t][r][b] = (b_ih[r]+b_hh[r]) + sum_k W_ih[r][k] * X[b][t][k]
// ---------------------------------------------------------------------------
__global__ __launch_bounds__(256) void pregemm(
    const float* __restrict__ X,    // [B][T][I]
    const float* __restrict__ Wih,  // [4H][I]
    const float* __restrict__ bih,
    const float* __restrict__ bhh,
    float* __restrict__ PG)         // [T][4H][B]
{
  __shared__ __align__(16) float Xs[64][68];
  __shared__ __align__(16) float Ws[64][68];
  const int t = blockIdx.x;
  const int rbase = blockIdx.y * 64;
  const int tid = threadIdx.x;
  const int cg = tid & 15;
  const int rg = tid >> 4;

  float acc[4][4] = {};

  for (int k0 = 0; k0 < II; k0 += 64) {
    {
      int b = tid >> 2, kq = tid & 3;
      const float* src = X + ((size_t)b * TT + t) * II + k0 + kq * 16;
      #pragma unroll
      for (int i = 0; i < 16; i += 4) {
        float4 v = *(const float4*)(src + i);
        int kk = kq * 16 + i;
        Xs[kk + 0][b] = v.x; Xs[kk + 1][b] = v.y;
        Xs[kk + 2][b] = v.z; Xs[kk + 3][b] = v.w;
      }
    }
    {
      int r = tid >> 2, kq = tid & 3;
      const float* src = Wih + (size_t)(rbase + r) * II + k0 + kq * 16;
      #pragma unroll
      for (int i = 0; i < 16; i += 4) {
        float4 v = *(const float4*)(src + i);
        int kk = kq * 16 + i;
        Ws[kk + 0][r] = v.x; Ws[kk + 1][r] = v.y;
        Ws[kk + 2][r] = v.z; Ws[kk + 3][r] = v.w;
      }
    }
    __syncthreads();
    #pragma unroll 8
    for (int kk = 0; kk < 64; ++kk) {
      float4 a = *(const float4*)&Ws[kk][rg * 4];
      float4 x = *(const float4*)&Xs[kk][cg * 4];
      float av[4] = {a.x, a.y, a.z, a.w};
      float xv[4] = {x.x, x.y, x.z, x.w};
      #pragma unroll
      for (int i = 0; i < 4; ++i)
        #pragma unroll
        for (int j = 0; j < 4; ++j)
          acc[i][j] = fmaf(av[i], xv[j], acc[i][j]);
    }
    __syncthreads();
  }

  #pragma unroll
  for (int i = 0; i < 4; ++i) {
    int row = rbase + rg * 4 + i;
    float bias = bih[row] + bhh[row];
    float4 o;
    o.x = acc[i][0] + bias; o.y = acc[i][1] + bias;
    o.z = acc[i][2] + bias; o.w = acc[i][3] + bias;
    *(float4*)&PG[((size_t)t * R4H + row) * BB + cg * 4] = o;
  }
}

// ---------------------------------------------------------------------------
// bf16 round-to-nearest-even (h magnitudes are finite, |h|<=1; no NaN path)
// ---------------------------------------------------------------------------
__device__ __forceinline__ uint32_t bf16r(float f) {
  uint32_t u = __float_as_uint(f);
  u += 0x7fffu + ((u >> 16) & 1u);
  return u >> 16;
}

// init: hb[0][uh][b] = pack(bf16(mem[b][256+2uh]), bf16(mem[b][256+2uh+1]))
__global__ void init_h(const float* __restrict__ mem, uint32_t* __restrict__ hb)
{
  int idx = blockIdx.x * 256 + threadIdx.x;
  if (idx < HB_STRIDE) {
    int uh = idx >> 6, b = idx & 63;
    float lo = mem[(size_t)b * 1280 + 256 + 2 * uh];
    float hi = mem[(size_t)b * 1280 + 256 + 2 * uh + 1];
    hb[idx] = bf16r(lo) | (bf16r(hi) << 16);
  }
}

// ---------------------------------------------------------------------------
// Cross-XCD h hand-off (proven R6): relaxed agent-scope EXCHANGE stores
// (RMW performed at the IF coherence point; vmcnt(0) ack => globally
// visible) + relaxed agent-scope loads (bypass stale L1/L2). RELAXED =>
// no wbl2/inv sweeps (the 91 us/step cost that killed R1).
// ---------------------------------------------------------------------------
__device__ __forceinline__ void store_coh_u32(uint32_t* p, uint32_t v) {
  (void)__hip_atomic_exchange(p, v, __ATOMIC_RELAXED, __HIP_MEMORY_SCOPE_AGENT);
}
__device__ __forceinline__ uint32_t load_coh_u32(const uint32_t* p) {
  return __hip_atomic_load(p, __ATOMIC_RELAXED, __HIP_MEMORY_SCOPE_AGENT);
}

// ---------------------------------------------------------------------------
// Persistent LSTM, batch-partitioned (R10): 8 INDEPENDENT groups of 32 WGs.
// Group gid = blockIdx>>5 owns batches [gid*8, gid*8+8) — batch rows are
// independent recurrences, so sync is per-group (32 WGs), not device-wide.
// WG owns 16 units (64 gate rows); W slice (64x512 f32 = 128 KB) lives in
// dynamic LDS, XOR-swizzled by row-group so 8 concurrent row-readers hit
// disjoint banks. Lane = (b = lane&7, rp = lane>>3): batch x row-group.
// Wave wu owns k-chunk [wu*64, +64). h bf16x2-packed (proven R7+).
// ---------------------------------------------------------------------------
__global__ __launch_bounds__(512) void lstm_persistent(
    const float* __restrict__ mem,   // [B][1280]
    const float* __restrict__ Whh,   // [4H][H]
    float* __restrict__ PG,          // [T][4H][B]
    uint32_t* __restrict__ hb,       // [2][HS/2][B] packed bf16x2
    float* __restrict__ outmem,      // [B][1280]
    unsigned* __restrict__ bar)      // grpcnt[8]@*32, gen[8]@1024+*32
{
  extern __shared__ float smem[];
  float4* Wlds4 = (float4*)smem;        // [64][128] float4  = 131072 B
  float*  part  = smem + 32768;         // [64][8][8] f32    =  16384 B
  float*  gsum  = part + 4096;          // [64][8] f32       =   2048 B

  const int g    = blockIdx.x;
  const int gid  = g >> 5;              // group 0..7
  const int mid  = g & 31;              // member 0..31
  const int ubase = mid * 16;           // first unit owned
  const int gb0  = gid * 8;             // first global batch

  const int tid  = threadIdx.x;
  const int wu   = tid >> 6;            // wave id = k-chunk
  const int lane = tid & 63;
  const int bl   = lane & 7;            // batch within group
  const int rp   = lane >> 3;           // row-group (8 rows each)

  unsigned* grpcnt = bar + gid * 32;
  unsigned* gen    = bar + 1024 + gid * 32;

  // ---- stage W slice into LDS, XOR-swizzled on k4 by row-group ----
  {
    const int lr = tid >> 3, kp = tid & 7;
    const int grow = (lr >> 4) * HS + ubase + (lr & 15);
    const int rpl = lr >> 3;
    const float* src = Whh + (size_t)grow * HS + kp * 64;
    #pragma unroll
    for (int i = 0; i < 16; ++i) {
      int kk4 = kp * 16 + i;
      float4 v = *(const float4*)(src + i * 4);
      Wlds4[lr * 128 + (kk4 ^ rpl)] = v;
    }
  }

  // elementwise state (tid < 128): unit uu_e = tid>>3, batch be = tid&7
  const int uu_e = tid >> 3, be = tid & 7;
  const int gbe = gb0 + be;
  float c_st = 0.f, m_st = 0.f, h_lastv = 0.f;
  if (tid < 128) {
    c_st = mem[(size_t)gbe * 1280 + 768 + ubase + uu_e];
    if (ubase < HHALF) m_st = mem[(size_t)gbe * 1280 + ubase + uu_e];
  }

  // reducer mapping: local row lrr = tid>>3 (0..63), batch br = tid&7
  const int lrr = tid >> 3, br = tid & 7;
  const int grow_r = (lrr >> 4) * HS + ubase + (lrr & 15);

  __syncthreads();  // W staged

  for (int t = 0; t < TT; ++t) {
    // prefetch this thread's pre-gate value (hidden under GEMM)
    float pg = PG[((size_t)t * R4H + grow_r) * BB + gb0 + br];

    // ---- coherent h loads: this lane's batch, this wave's k-chunk ----
    const uint32_t* hbase = hb + (size_t)(t & 1) * HB_STRIDE
                               + (size_t)(wu * 32) * BB + gb0 + bl;
    uint32_t hpk[32];
    #pragma unroll
    for (int j = 0; j < 32; ++j) hpk[j] = load_coh_u32(hbase + (size_t)j * BB);

    // ---- recurrent GEMM: 8 rows x 64 k per lane, W via swizzled LDS ----
    float acc[8] = {0, 0, 0, 0, 0, 0, 0, 0};
    const int rbase = rp * 8 * 128;
    #pragma unroll
    for (int k4 = 0; k4 < 16; ++k4) {
      uint32_t p0 = hpk[2 * k4], p1 = hpk[2 * k4 + 1];
      float h0 = __int_as_float(p0 << 16);
      float h1 = __int_as_float(p0 & 0xffff0000u);
      float h2 = __int_as_float(p1 << 16);
      float h3 = __int_as_float(p1 & 0xffff0000u);
      int kx = (wu * 16 + k4) ^ rp;
      #pragma unroll
      for (int rr = 0; rr < 8; ++rr) {
        float4 w = Wlds4[rbase + rr * 128 + kx];
        acc[rr] = fmaf(w.x, h0, acc[rr]);
        acc[rr] = fmaf(w.y, h1, acc[rr]);
        acc[rr] = fmaf(w.z, h2, acc[rr]);
        acc[rr] = fmaf(w.w, h3, acc[rr]);
      }
    }
    #pragma unroll
    for (int rr = 0; rr < 8; ++rr)
      part[(rp * 8 + rr) * 64 + bl * 8 + wu] = acc[rr];
    __syncthreads();

    // ---- reduce 8 wave-partials + pg -> gsum ----
    {
      float s = pg;
      const float* pp = part + lrr * 64 + br * 8;
      #pragma unroll
      for (int w8 = 0; w8 < 8; ++w8) s += pp[w8];
      gsum[lrr * 8 + br] = s;
    }
    __syncthreads();

    // ---- elementwise LSTM cell + running cmax (tid < 128) ----
    if (tid < 128) {
      float gi = gsum[( 0 + uu_e) * 8 + be];
      float gf = gsum[(16 + uu_e) * 8 + be];
      float gg = gsum[(32 + uu_e) * 8 + be];
      float go = gsum[(48 + uu_e) * 8 + be];
      float si = 1.f / (1.f + __expf(-gi));
      float sf = 1.f / (1.f + __expf(-gf));
      float so = 1.f / (1.f + __expf(-go));
      c_st = sf * c_st + si * tanhf(gg);
      float hv = so * tanhf(c_st);
      h_lastv = hv;
      // pack unit-pair (uu even with uu+1 = lane+8, same wave) and store
      float hnb = __shfl_down(hv, 8);
      if ((tid & 8) == 0) {
        uint32_t pk = bf16r(hv) | (bf16r(hnb) << 16);
        int uhg = (ubase + uu_e) >> 1;
        store_coh_u32(&hb[(size_t)((t + 1) & 1) * HB_STRIDE
                          + (size_t)uhg * BB + gbe], pk);
      }
      float outv = hv;
      if (ubase < HHALF) { m_st = fmaxf(m_st, hv); outv = m_st; }
      PG[((size_t)t * R4H + ubase + uu_e) * BB + gbe] = outv;  // stash
    }

    // ---- group barrier: release = vmcnt(0) on the exchange h-stores ----
    asm volatile("s_waitcnt vmcnt(0)" ::: "memory");
    __syncthreads();
    if (tid == 0) {
      unsigned a = __hip_atomic_fetch_add(grpcnt, 1u, __ATOMIC_RELAXED,
                                          __HIP_MEMORY_SCOPE_AGENT);
      if (a == 32u * (unsigned)(t + 1) - 1u)
        (void)__hip_atomic_exchange(gen, (unsigned)(t + 1), __ATOMIC_RELAXED,
                                    __HIP_MEMORY_SCOPE_AGENT);
      // failsafe cap: fast wrong-answer instead of a hang; expected wait ~us.
      int spins = 0;
      while (__hip_atomic_load(gen, __ATOMIC_RELAXED,
                               __HIP_MEMORY_SCOPE_AGENT) < (unsigned)(t + 1)) {
        __builtin_amdgcn_s_sleep(1);
        if (++spins > (1 << 16)) break;
      }
    }
    __syncthreads();
  }

  if (tid < 128) {
    outmem[(size_t)gbe * 1280 + 256 + ubase + uu_e] = h_lastv;
    outmem[(size_t)gbe * 1280 + 768 + ubase + uu_e] = c_st;
    if (ubase < HHALF) outmem[(size_t)gbe * 1280 + ubase + uu_e] = m_st;
  }
}

// ---------------------------------------------------------------------------
// Phase 3: out[b][t][u] = PG[t][u][b]  (u < 512)
// ---------------------------------------------------------------------------
__global__ __launch_bounds__(256) void transpose_out(
    const float* __restrict__ PG, float* __restrict__ out)
{
  __shared__ __align__(16) float tileS[64][68];
  const int t = blockIdx.x;
  const int u0 = blockIdx.y * 64;
  const int tid = threadIdx.x;

  {
    int cg = tid & 15, rg = tid >> 4;
    const float* src = PG + (size_t)t * R4H * BB + (size_t)u0 * BB;
    #pragma unroll
    for (int i = 0; i < 4; ++i) {
      int u = rg * 4 + i;
      float4 v = *(const float4*)(src + (size_t)u * BB + cg * 4);
      *(float4*)&tileS[u][cg * 4] = v;
    }
  }
  __syncthreads();
  {
    int ug = tid & 15, bg = tid >> 4;
    #pragma unroll
    for (int i = 0; i < 4; ++i) {
      int b = bg * 4 + i;
      float4 o;
      o.x = tileS[ug * 4 + 0][b];
      o.y = tileS[ug * 4 + 1][b];
      o.z = tileS[ug * 4 + 2][b];
      o.w = tileS[ug * 4 + 3][b];
      *(float4*)&out[((size_t)b * TT + t) * HS + u0 + ug * 4] = o;
    }
  }
}

// ---------------------------------------------------------------------------
extern "C" void kernel_launch(void* const* d_in, const int* in_sizes, int n_in,
                              void* d_out, int out_size, void* d_ws, size_t ws_size,
                              hipStream_t stream)
{
  const float* X   = (const float*)d_in[0];
  const float* mem = (const float*)d_in[1];
  const float* Wih = (const float*)d_in[2];
  const float* Whh = (const float*)d_in[3];
  const float* bih = (const float*)d_in[4];
  const float* bhh = (const float*)d_in[5];

  float* out = (float*)d_out;
  float* outmem = out + (size_t)BB * TT * HS;

  float* PG    = (float*)d_ws;                       // 512*2048*64 f32 = 256 MB
  uint32_t* hbp = (uint32_t*)(PG + (size_t)TT * R4H * BB);  // 2*16384 u32
  unsigned* bar = (unsigned*)(hbp + 2 * HB_STRIDE);  // 2048 u32

  const int dyn_lds = 149504;  // 131072 (W) + 16384 (part) + 2048 (gsum)
  (void)hipFuncSetAttribute((const void*)lstm_persistent,
                            hipFuncAttributeMaxDynamicSharedMemorySize, dyn_lds);

  hipMemsetAsync(bar, 0, 2048 * sizeof(unsigned), stream);
  init_h<<<dim3((HB_STRIDE + 255) / 256), dim3(256), 0, stream>>>(mem, hbp);
  pregemm<<<dim3(TT, 32), dim3(256), 0, stream>>>(X, Wih, bih, bhh, PG);
  lstm_persistent<<<dim3(256), dim3(512), dyn_lds, stream>>>(mem, Whh, PG, hbp, outmem, bar);
  transpose_out<<<dim3(TT, 8), dim3(256), 0, stream>>>(PG, out);
}

// Round 11
// 3344.202 us; speedup vs baseline: 1.1021x; 1.1021x over previous
//
#include <hip/hip_runtime.h>
#include <stdint.h>

#define TT 512
#define BB 64
#define II 256
#define HS 512          // H
#define HHALF 256       // HH
#define R4H 2048        // 4*H
#define HB_STRIDE 16384 // (HS/2)*BB u32 entries per h buffer

// ---------------------------------------------------------------------------
// Phase 1: PG[t][r][b] = (b_ih[r]+b_hh[r]) + sum_k W_ih[r][k] * X[b][t][k]
// ---------------------------------------------------------------------------
__global__ __launch_bounds__(256) void pregemm(
    const float* __restrict__ X,    // [B][T][I]
    const float* __restrict__ Wih,  // [4H][I]
    const float* __restrict__ bih,
    const float* __restrict__ bhh,
    float* __restrict__ PG)         // [T][4H][B]
{
  __shared__ __align__(16) float Xs[64][68];
  __shared__ __align__(16) float Ws[64][68];
  const int t = blockIdx.x;
  const int rbase = blockIdx.y * 64;
  const int tid = threadIdx.x;
  const int cg = tid & 15;
  const int rg = tid >> 4;

  float acc[4][4] = {};

  for (int k0 = 0; k0 < II; k0 += 64) {
    {
      int b = tid >> 2, kq = tid & 3;
      const float* src = X + ((size_t)b * TT + t) * II + k0 + kq * 16;
      #pragma unroll
      for (int i = 0; i < 16; i += 4) {
        float4 v = *(const float4*)(src + i);
        int kk = kq * 16 + i;
        Xs[kk + 0][b] = v.x; Xs[kk + 1][b] = v.y;
        Xs[kk + 2][b] = v.z; Xs[kk + 3][b] = v.w;
      }
    }
    {
      int r = tid >> 2, kq = tid & 3;
      const float* src = Wih + (size_t)(rbase + r) * II + k0 + kq * 16;
      #pragma unroll
      for (int i = 0; i < 16; i += 4) {
        float4 v = *(const float4*)(src + i);
        int kk = kq * 16 + i;
        Ws[kk + 0][r] = v.x; Ws[kk + 1][r] = v.y;
        Ws[kk + 2][r] = v.z; Ws[kk + 3][r] = v.w;
      }
    }
    __syncthreads();
    #pragma unroll 8
    for (int kk = 0; kk < 64; ++kk) {
      float4 a = *(const float4*)&Ws[kk][rg * 4];
      float4 x = *(const float4*)&Xs[kk][cg * 4];
      float av[4] = {a.x, a.y, a.z, a.w};
      float xv[4] = {x.x, x.y, x.z, x.w};
      #pragma unroll
      for (int i = 0; i < 4; ++i)
        #pragma unroll
        for (int j = 0; j < 4; ++j)
          acc[i][j] = fmaf(av[i], xv[j], acc[i][j]);
    }
    __syncthreads();
  }

  #pragma unroll
  for (int i = 0; i < 4; ++i) {
    int row = rbase + rg * 4 + i;
    float bias = bih[row] + bhh[row];
    float4 o;
    o.x = acc[i][0] + bias; o.y = acc[i][1] + bias;
    o.z = acc[i][2] + bias; o.w = acc[i][3] + bias;
    *(float4*)&PG[((size_t)t * R4H + row) * BB + cg * 4] = o;
  }
}

// ---------------------------------------------------------------------------
// bf16 round-to-nearest-even (h magnitudes are finite, |h|<=1; no NaN path)
// ---------------------------------------------------------------------------
__device__ __forceinline__ uint32_t bf16r(float f) {
  uint32_t u = __float_as_uint(f);
  u += 0x7fffu + ((u >> 16) & 1u);
  return u >> 16;
}

// init: hb[0][uh][b] = pack(bf16(mem[b][256+2uh]), bf16(mem[b][256+2uh+1]))
__global__ void init_h(const float* __restrict__ mem, uint32_t* __restrict__ hb)
{
  int idx = blockIdx.x * 256 + threadIdx.x;
  if (idx < HB_STRIDE) {
    int uh = idx >> 6, b = idx & 63;
    float lo = mem[(size_t)b * 1280 + 256 + 2 * uh];
    float hi = mem[(size_t)b * 1280 + 256 + 2 * uh + 1];
    hb[idx] = bf16r(lo) | (bf16r(hi) << 16);
  }
}

// ---------------------------------------------------------------------------
// Cross-XCD h hand-off (proven R6): relaxed agent-scope EXCHANGE stores
// (RMW performed at the IF coherence point; vmcnt(0) ack => globally
// visible) + relaxed agent-scope loads (bypass stale L1/L2). RELAXED =>
// no wbl2/inv sweeps (the 91 us/step cost that killed R1).
// ---------------------------------------------------------------------------
__device__ __forceinline__ void store_coh_u32(uint32_t* p, uint32_t v) {
  (void)__hip_atomic_exchange(p, v, __ATOMIC_RELAXED, __HIP_MEMORY_SCOPE_AGENT);
}
__device__ __forceinline__ uint32_t load_coh_u32(const uint32_t* p) {
  return __hip_atomic_load(p, __ATOMIC_RELAXED, __HIP_MEMORY_SCOPE_AGENT);
}

// ---------------------------------------------------------------------------
// Persistent LSTM, batch-partitioned (R10) + conflict-free LDS maps (R11).
// 8 independent groups of 32 WGs; group gid owns batches [gid*8, gid*8+8).
// WG owns 16 units (64 gate rows); W slice (128 KB) in dynamic LDS,
// XOR-swizzled on k4 by row-group (conflict-free, verified R10 counters).
// R11 fixes: part scatter was 8/16-way bank-conflicted (2.37e8 extra cyc).
//  - write  part[row*64 + ((bl*8+wu)^rp)]          -> 32 banks x 2 lanes
//  - reducer owns (row_r=(lane&7)*8+wu, b_r=lane>>3);
//    read   part[row_r*64 + ((b_r*8+w8)^(lane&7))] -> 32 banks x 2 lanes
//  - gsum stride 9: write/read <=2-way
//  - pg prefetch for t+1 issued after the vmcnt drain -> hides under barrier
// ---------------------------------------------------------------------------
__global__ __launch_bounds__(512) void lstm_persistent(
    const float* __restrict__ mem,   // [B][1280]
    const float* __restrict__ Whh,   // [4H][H]
    float* __restrict__ PG,          // [T][4H][B]
    uint32_t* __restrict__ hb,       // [2][HS/2][B] packed bf16x2
    float* __restrict__ outmem,      // [B][1280]
    unsigned* __restrict__ bar)      // grpcnt[8]@*32, gen[8]@1024+*32
{
  extern __shared__ float smem[];
  float4* Wlds4 = (float4*)smem;        // [64][128] float4  = 131072 B
  float*  part  = smem + 32768;         // [64][64] f32      =  16384 B
  float*  gsum  = part + 4096;          // [64][9] f32       =   2304 B

  const int g    = blockIdx.x;
  const int gid  = g >> 5;              // group 0..7
  const int mid  = g & 31;              // member 0..31
  const int ubase = mid * 16;           // first unit owned
  const int gb0  = gid * 8;             // first global batch

  const int tid  = threadIdx.x;
  const int wu   = tid >> 6;            // wave id = k-chunk
  const int lane = tid & 63;
  const int bl   = lane & 7;            // GEMM: batch within group
  const int rp   = lane >> 3;           // GEMM: row-group (8 rows each)

  // reducer mapping (conflict-free): row_r in [0,64), b_r in [0,8)
  const int row_r = (lane & 7) * 8 + wu;
  const int b_r   = lane >> 3;
  const int grow_r = (row_r >> 4) * HS + ubase + (row_r & 15);

  unsigned* grpcnt = bar + gid * 32;
  unsigned* gen    = bar + 1024 + gid * 32;

  // ---- stage W slice into LDS, XOR-swizzled on k4 by row-group ----
  {
    const int lr = tid >> 3, kp = tid & 7;
    const int grow = (lr >> 4) * HS + ubase + (lr & 15);
    const int rpl = lr >> 3;
    const float* src = Whh + (size_t)grow * HS + kp * 64;
    #pragma unroll
    for (int i = 0; i < 16; ++i) {
      int kk4 = kp * 16 + i;
      float4 v = *(const float4*)(src + i * 4);
      Wlds4[lr * 128 + (kk4 ^ rpl)] = v;
    }
  }

  // elementwise state (tid < 128): unit uu_e = tid>>3, batch be = tid&7
  const int uu_e = tid >> 3, be = tid & 7;
  const int gbe = gb0 + be;
  float c_st = 0.f, m_st = 0.f, h_lastv = 0.f;
  if (tid < 128) {
    c_st = mem[(size_t)gbe * 1280 + 768 + ubase + uu_e];
    if (ubase < HHALF) m_st = mem[(size_t)gbe * 1280 + ubase + uu_e];
  }

  __syncthreads();  // W staged

  // prefetch pre-gate value for t=0 (this thread's (row_r, b_r))
  float pg = PG[((size_t)0 * R4H + grow_r) * BB + gb0 + b_r];

  for (int t = 0; t < TT; ++t) {
    // ---- coherent h loads: this lane's batch, this wave's k-chunk ----
    const uint32_t* hbase = hb + (size_t)(t & 1) * HB_STRIDE
                               + (size_t)(wu * 32) * BB + gb0 + bl;
    uint32_t hpk[32];
    #pragma unroll
    for (int j = 0; j < 32; ++j) hpk[j] = load_coh_u32(hbase + (size_t)j * BB);

    // ---- recurrent GEMM: 8 rows x 64 k per lane, W via swizzled LDS ----
    float acc[8] = {0, 0, 0, 0, 0, 0, 0, 0};
    const int rbase = rp * 8 * 128;
    #pragma unroll
    for (int k4 = 0; k4 < 16; ++k4) {
      uint32_t p0 = hpk[2 * k4], p1 = hpk[2 * k4 + 1];
      float h0 = __int_as_float(p0 << 16);
      float h1 = __int_as_float(p0 & 0xffff0000u);
      float h2 = __int_as_float(p1 << 16);
      float h3 = __int_as_float(p1 & 0xffff0000u);
      int kx = (wu * 16 + k4) ^ rp;
      #pragma unroll
      for (int rr = 0; rr < 8; ++rr) {
        float4 w = Wlds4[rbase + rr * 128 + kx];
        acc[rr] = fmaf(w.x, h0, acc[rr]);
        acc[rr] = fmaf(w.y, h1, acc[rr]);
        acc[rr] = fmaf(w.z, h2, acc[rr]);
        acc[rr] = fmaf(w.w, h3, acc[rr]);
      }
    }
    // conflict-free part scatter: bank = (wu^rp) + 8*(bl&3), 2 lanes/bank
    #pragma unroll
    for (int rr = 0; rr < 8; ++rr)
      part[(rp * 8 + rr) * 64 + ((bl * 8 + wu) ^ rp)] = acc[rr];
    __syncthreads();

    // ---- reduce 8 wave-partials + pg -> gsum (conflict-free reads) ----
    {
      float s = pg;
      const int pr = row_r * 64;
      const int sw = lane & 7;   // == row_r>>3
      #pragma unroll
      for (int w8 = 0; w8 < 8; ++w8)
        s += part[pr + ((b_r * 8 + w8) ^ sw)];
      gsum[row_r * 9 + b_r] = s;
    }
    __syncthreads();

    // ---- elementwise LSTM cell + running cmax (tid < 128) ----
    if (tid < 128) {
      float gi = gsum[( 0 + uu_e) * 9 + be];
      float gf = gsum[(16 + uu_e) * 9 + be];
      float gg = gsum[(32 + uu_e) * 9 + be];
      float go = gsum[(48 + uu_e) * 9 + be];
      float si = 1.f / (1.f + __expf(-gi));
      float sf = 1.f / (1.f + __expf(-gf));
      float so = 1.f / (1.f + __expf(-go));
      c_st = sf * c_st + si * tanhf(gg);
      float hv = so * tanhf(c_st);
      h_lastv = hv;
      // pack unit-pair (uu even with uu+1 = tid+8, same wave) and store
      float hnb = __shfl_down(hv, 8);
      if ((tid & 8) == 0) {
        uint32_t pk = bf16r(hv) | (bf16r(hnb) << 16);
        int uhg = (ubase + uu_e) >> 1;
        store_coh_u32(&hb[(size_t)((t + 1) & 1) * HB_STRIDE
                          + (size_t)uhg * BB + gbe], pk);
      }
      float outv = hv;
      if (ubase < HHALF) { m_st = fmaxf(m_st, hv); outv = m_st; }
      PG[((size_t)t * R4H + ubase + uu_e) * BB + gbe] = outv;  // stash
    }

    // ---- group barrier: release = vmcnt(0) on the exchange h-stores ----
    asm volatile("s_waitcnt vmcnt(0)" ::: "memory");
    __syncthreads();
    // issue next-step pg prefetch NOW: ~HBM latency hides under the barrier
    if (t + 1 < TT)
      pg = PG[((size_t)(t + 1) * R4H + grow_r) * BB + gb0 + b_r];
    if (tid == 0) {
      unsigned a = __hip_atomic_fetch_add(grpcnt, 1u, __ATOMIC_RELAXED,
                                          __HIP_MEMORY_SCOPE_AGENT);
      if (a == 32u * (unsigned)(t + 1) - 1u)
        (void)__hip_atomic_exchange(gen, (unsigned)(t + 1), __ATOMIC_RELAXED,
                                    __HIP_MEMORY_SCOPE_AGENT);
      // failsafe cap: fast wrong-answer instead of a hang; expected wait ~us.
      int spins = 0;
      while (__hip_atomic_load(gen, __ATOMIC_RELAXED,
                               __HIP_MEMORY_SCOPE_AGENT) < (unsigned)(t + 1)) {
        __builtin_amdgcn_s_sleep(1);
        if (++spins > (1 << 16)) break;
      }
    }
    __syncthreads();
  }

  if (tid < 128) {
    outmem[(size_t)gbe * 1280 + 256 + ubase + uu_e] = h_lastv;
    outmem[(size_t)gbe * 1280 + 768 + ubase + uu_e] = c_st;
    if (ubase < HHALF) outmem[(size_t)gbe * 1280 + ubase + uu_e] = m_st;
  }
}

// ---------------------------------------------------------------------------
// Phase 3: out[b][t][u] = PG[t][u][b]  (u < 512)
// ---------------------------------------------------------------------------
__global__ __launch_bounds__(256) void transpose_out(
    const float* __restrict__ PG, float* __restrict__ out)
{
  __shared__ __align__(16) float tileS[64][68];
  const int t = blockIdx.x;
  const int u0 = blockIdx.y * 64;
  const int tid = threadIdx.x;

  {
    int cg = tid & 15, rg = tid >> 4;
    const float* src = PG + (size_t)t * R4H * BB + (size_t)u0 * BB;
    #pragma unroll
    for (int i = 0; i < 4; ++i) {
      int u = rg * 4 + i;
      float4 v = *(const float4*)(src + (size_t)u * BB + cg * 4);
      *(float4*)&tileS[u][cg * 4] = v;
    }
  }
  __syncthreads();
  {
    int ug = tid & 15, bg = tid >> 4;
    #pragma unroll
    for (int i = 0; i < 4; ++i) {
      int b = bg * 4 + i;
      float4 o;
      o.x = tileS[ug * 4 + 0][b];
      o.y = tileS[ug * 4 + 1][b];
      o.z = tileS[ug * 4 + 2][b];
      o.w = tileS[ug * 4 + 3][b];
      *(float4*)&out[((size_t)b * TT + t) * HS + u0 + ug * 4] = o;
    }
  }
}

// ---------------------------------------------------------------------------
extern "C" void kernel_launch(void* const* d_in, const int* in_sizes, int n_in,
                              void* d_out, int out_size, void* d_ws, size_t ws_size,
                              hipStream_t stream)
{
  const float* X   = (const float*)d_in[0];
  const float* mem = (const float*)d_in[1];
  const float* Wih = (const float*)d_in[2];
  const float* Whh = (const float*)d_in[3];
  const float* bih = (const float*)d_in[4];
  const float* bhh = (const float*)d_in[5];

  float* out = (float*)d_out;
  float* outmem = out + (size_t)BB * TT * HS;

  float* PG    = (float*)d_ws;                       // 512*2048*64 f32 = 256 MB
  uint32_t* hbp = (uint32_t*)(PG + (size_t)TT * R4H * BB);  // 2*16384 u32
  unsigned* bar = (unsigned*)(hbp + 2 * HB_STRIDE);  // 2048 u32

  const int dyn_lds = 149760;  // 131072 (W) + 16384 (part) + 2304 (gsum)
  (void)hipFuncSetAttribute((const void*)lstm_persistent,
                            hipFuncAttributeMaxDynamicSharedMemorySize, dyn_lds);

  hipMemsetAsync(bar, 0, 2048 * sizeof(unsigned), stream);
  init_h<<<dim3((HB_STRIDE + 255) / 256), dim3(256), 0, stream>>>(mem, hbp);
  pregemm<<<dim3(TT, 32), dim3(256), 0, stream>>>(X, Wih, bih, bhh, PG);
  lstm_persistent<<<dim3(256), dim3(512), dyn_lds, stream>>>(mem, Whh, PG, hbp, outmem, bar);
  transpose_out<<<dim3(TT, 8), dim3(256), 0, stream>>>(PG, out);
}